// Round 5
// baseline (33004.822 us; speedup 1.0000x reference)
//
#include <hip/hip_runtime.h>

#define MAXD 192
#define NCH  16

#define RFL_I(x) __builtin_amdgcn_readfirstlane(x)
#define RFL_F(x) __int_as_float(__builtin_amdgcn_readfirstlane(__float_as_int(x)))
#define RDL(v,k) __int_as_float(__builtin_amdgcn_readlane(__float_as_int(v), (k)))
#define LOADF(p, boff) (*(const float*)((p) + (boff)))

// One block per (point n = blockIdx.x, level j = blockIdx.y).
// Waves 0-2: pass-1 (scale 1) disparity chunks of 64. Wave 3: pass-0 (scale 4, D=48).
// Per channel: 28 raw global loads are issued one channel AHEAD (register
// pipeline); bilinear weights/masks/addresses are all channel-invariant and
// hoisted. Left 5x5 window is broadcast via v_readlane (no LDS round-trip).
__global__ __launch_bounds__(256, 6) void pbm_kernel(
    const float* __restrict__ lfeat,   // (16,1,16,H,W)
    const float* __restrict__ rfeat,
    const float* __restrict__ points,  // (1,N,2)
    const int* __restrict__ pW, const int* __restrict__ pH,
    float* __restrict__ out)           // (1,N,192,8)
{
    const int W = RFL_I(*pW), H = RFL_I(*pH);
    const int HW = W * H;
    const int n   = blockIdx.x;
    const int j   = blockIdx.y;        // linear id = j*N+n; N%8==0 -> same-n same XCD
    const int tid = threadIdx.x;
    const int wv  = tid >> 6;
    const int l   = tid & 63;

    const float pxr = points[2 * n];
    const float pyr = points[2 * n + 1];
    const float pxf = floorf(pxr), pyf = floorf(pyr);
    const float fx  = RFL_F(pxr - pxf);
    const float fy  = RFL_F(pyr - pyf);
    const int   x0i = RFL_I((int)pxf);
    const int   y0i = RFL_I((int)pyf);

    __shared__ float sv[4][5][68];     // per-wave right strip
    __shared__ float val4[48];

    const bool p0  = (wv == 3);
    const int  s_  = p0 ? 4 : 1;
    const int  lvl = p0 ? j + 8 : j;
    const int  off = p0 ? 49 : wv * 64 + 65;
    const int  DC  = p0 ? 48 : 64;

    // ---- strip column consts (col == lane), byte offsets ----
    const int   cx   = x0i + s_ * (l - off);
    const int   cbo0 = min(max(cx, 0), W - 1) * 4;
    const int   cbo1 = min(max(cx + 1, 0), W - 1) * 4;
    const float mx0  = ((unsigned)cx       < (unsigned)W) ? 1.0f : 0.0f;
    const float mx1  = ((unsigned)(cx + 1) < (unsigned)W) ? 1.0f : 0.0f;

    // ---- cleanup taps: cols 64+(l&3), row l>>2; only lanes<20 write ----
    const int   dyc  = min(l >> 2, 4);
    const int   dcol = 64 + (l & 3);
    const int   dcx  = x0i + s_ * (dcol - off);
    const int   dbo0 = min(max(dcx, 0), W - 1) * 4;
    const int   dbo1 = min(max(dcx + 1, 0), W - 1) * 4;
    const float dmx0 = ((unsigned)dcx       < (unsigned)W) ? 1.0f : 0.0f;
    const float dmx1 = ((unsigned)(dcx + 1) < (unsigned)W) ? 1.0f : 0.0f;
    const int   dyr  = y0i + s_ * (dyc - 2);
    const int   dybo0 = min(max(dyr, 0), H - 1) * W * 4;
    const int   dybo1 = min(max(dyr + 1, 0), H - 1) * W * 4;
    const float dwy0 = ((unsigned)dyr       < (unsigned)H) ? (1.0f - fy) : 0.0f;
    const float dwy1 = ((unsigned)(dyr + 1) < (unsigned)H) ? fy : 0.0f;
    const int   vx0 = dybo0 + dbo0, vx1 = dybo0 + dbo1;
    const int   vx2 = dybo1 + dbo0, vx3 = dybo1 + dbo1;

    // ---- left window taps: lanes 0..24 meaningful ----
    const int   lw  = min(l, 24);
    const int   lyy = lw / 5;
    const int   lxx = lw - lyy * 5;
    const int   lx  = x0i + s_ * (lxx - 2);
    const int   ly  = y0i + s_ * (lyy - 2);
    const int   la0 = min(max(lx, 0), W - 1) * 4;
    const int   la1 = min(max(lx + 1, 0), W - 1) * 4;
    const int   lb0 = min(max(ly, 0), H - 1) * W * 4;
    const int   lb1 = min(max(ly + 1, 0), H - 1) * W * 4;
    const float lmx0 = ((unsigned)lx       < (unsigned)W) ? 1.0f : 0.0f;
    const float lmx1 = ((unsigned)(lx + 1) < (unsigned)W) ? 1.0f : 0.0f;
    const float lwy0 = ((unsigned)ly       < (unsigned)H) ? (1.0f - fy) : 0.0f;
    const float lwy1 = ((unsigned)(ly + 1) < (unsigned)H) ? fy : 0.0f;
    const int   lo0 = lb0 + la0, lo1 = lb0 + la1, lo2 = lb1 + la0, lo3 = lb1 + la1;

    // ---- wave-uniform row consts (SGPR) ----
    int s_ybo0[5], s_ybo1[5]; float s_wy0[5], s_wy1[5];
#pragma unroll
    for (int yy = 0; yy < 5; ++yy) {
        int yr = y0i + s_ * (yy - 2);
        s_ybo0[yy] = min(max(yr, 0), H - 1) * W * 4;
        s_ybo1[yy] = min(max(yr + 1, 0), H - 1) * W * 4;
        s_wy0[yy]  = ((unsigned)yr       < (unsigned)H) ? (1.0f - fy) : 0.0f;
        s_wy1[yy]  = ((unsigned)(yr + 1) < (unsigned)H) ? fy : 0.0f;
    }

    const char* Rb = (const char*)rfeat + (size_t)lvl * NCH * HW * 4;
    const char* Lb = (const char*)lfeat + (size_t)lvl * NCH * HW * 4;
    const size_t HW4 = (size_t)HW * 4;

    // hoisted LDS vaddrs (lane-constant)
    float* swr = &sv[wv][0][l];            // strip row write base (stride 68)
    float* swx = &sv[wv][dyc][dcol];       // cleanup write
    const int b0 = DC - 1 - l;             // may be <0 for p0 lanes 48-63 (junk, unused)
    const float* srd = &sv[wv][0][b0];     // compute read base (stride 68)

    float r[5][4], rx[4], rl[4];

#define ISSUE(c_) do {                                                     \
    const char* Rp_ = Rb + (size_t)(c_) * HW4;                             \
    const char* Lp_ = Lb + (size_t)(c_) * HW4;                             \
    _Pragma("unroll")                                                      \
    for (int yy = 0; yy < 5; ++yy) {                                       \
        r[yy][0] = LOADF(Rp_ + s_ybo0[yy], cbo0);                          \
        r[yy][1] = LOADF(Rp_ + s_ybo0[yy], cbo1);                          \
        r[yy][2] = LOADF(Rp_ + s_ybo1[yy], cbo0);                          \
        r[yy][3] = LOADF(Rp_ + s_ybo1[yy], cbo1);                          \
    }                                                                      \
    rx[0] = LOADF(Rp_, vx0); rx[1] = LOADF(Rp_, vx1);                      \
    rx[2] = LOADF(Rp_, vx2); rx[3] = LOADF(Rp_, vx3);                      \
    rl[0] = LOADF(Lp_, lo0); rl[1] = LOADF(Lp_, lo1);                      \
    rl[2] = LOADF(Lp_, lo2); rl[3] = LOADF(Lp_, lo3);                      \
} while (0)

    float acc = 0.0f;
    ISSUE(0);

#pragma unroll 1
    for (int c = 0; c < NCH; ++c) {
        // lerp staged raw -> strip LDS
#pragma unroll
        for (int yy = 0; yy < 5; ++yy) {
            float v00 = r[yy][0] * mx0, v01 = r[yy][1] * mx1;
            float v10 = r[yy][2] * mx0, v11 = r[yy][3] * mx1;
            float t = v00 + fx * (v01 - v00);
            float b = v10 + fx * (v11 - v10);
            swr[yy * 68] = t * s_wy0[yy] + b * s_wy1[yy];
        }
        {
            float v00 = rx[0] * dmx0, v01 = rx[1] * dmx1;
            float v10 = rx[2] * dmx0, v11 = rx[3] * dmx1;
            float t = v00 + fx * (v01 - v00);
            float b = v10 + fx * (v11 - v10);
            float xv = t * dwy0 + b * dwy1;
            if (l < 20) *swx = xv;
        }
        float lval;
        {
            float v00 = rl[0] * lmx0, v01 = rl[1] * lmx1;
            float v10 = rl[2] * lmx0, v11 = rl[3] * lmx1;
            float t = v00 + fx * (v01 - v00);
            float b = v10 + fx * (v11 - v10);
            lval = t * lwy0 + b * lwy1;
        }

        if (c + 1 < NCH) ISSUE(c + 1);   // next channel's loads in flight

        // broadcast left window to SGPRs
        float sk[25];
#pragma unroll
        for (int k = 0; k < 25; ++k) sk[k] = RDL(lval, k);

        asm volatile("s_waitcnt lgkmcnt(0)" ::: "memory");
        __builtin_amdgcn_sched_barrier(0);

        float a0 = 0.f, a1 = 0.f;
#pragma unroll
        for (int yy = 0; yy < 5; ++yy) {
            const float* rp = srd + yy * 68;
            float w0 = rp[0], w1 = rp[1], w2 = rp[2], w3 = rp[3], w4 = rp[4];
            a0 += fabsf(sk[yy * 5 + 0] - w0);
            a1 += fabsf(sk[yy * 5 + 1] - w1);
            a0 += fabsf(sk[yy * 5 + 2] - w2);
            a1 += fabsf(sk[yy * 5 + 3] - w3);
            a0 += fabsf(sk[yy * 5 + 4] - w4);
        }
        acc += a0 + a1;
    }

    if (p0 && l < 48)
        val4[l] = 1.0f - expf(-acc * (1.0f / 400.0f));

    __syncthreads();                     // only block-wide barrier

    if (tid < MAXD) {                    // waves 0-2: d == tid
        float v1  = 1.0f - expf(-acc * (1.0f / 400.0f));
        float pos = (float)tid * (47.0f / 191.0f);
        float i0f = floorf(pos);
        int   i0  = (int)i0f;
        float w   = pos - i0f;
        int   i1  = min(i0 + 1, 47);
        float up  = val4[i0] + w * (val4[i1] - val4[i0]);
        out[((size_t)n * MAXD + tid) * 8 + j] = v1 + up;
    }
}

extern "C" void kernel_launch(void* const* d_in, const int* in_sizes, int n_in,
                              void* d_out, int out_size, void* d_ws, size_t ws_size,
                              hipStream_t stream) {
    const float* lf  = (const float*)d_in[0];
    const float* rf  = (const float*)d_in[1];
    const float* pts = (const float*)d_in[2];
    const int*   pW  = (const int*)d_in[3];
    const int*   pH  = (const int*)d_in[4];
    float* out = (float*)d_out;

    const int N = in_sizes[2] / 2;       // (B=1, N, 2)
    pbm_kernel<<<dim3(N, 8), 256, 0, stream>>>(lf, rf, pts, pW, pH, out);
}

// Round 6
// 952.187 us; speedup vs baseline: 34.6621x; 34.6621x over previous
//
#include <hip/hip_runtime.h>

#define MAXD 192
#define NCH  16

#define RFL_I(x) __builtin_amdgcn_readfirstlane(x)
#define RFL_F(x) __int_as_float(__builtin_amdgcn_readfirstlane(__float_as_int(x)))
#define LOADF(base, off) (*(const float*)((base) + (off)))

// One block per (point n = blockIdx.x, level j = blockIdx.y).
// Waves 0-2: pass-1 (scale 1) disparity chunks [0,64),[64,128),[128,192).
// Wave 3:   pass-0 (scale 4, D=48), level j+8.
// Each wave stages its private LDS strip; NO inter-wave barriers except the
// final val4 handoff. All bilinear fractional weights / validity masks are
// block constants (coords are p + s*integer); masks folded into corner
// weights ax0/ax1 (x) and by0/by1 (y). No asm fences: compiler handles
// wave-private LDS ordering and pipelines the global loads across channels.
__global__ __launch_bounds__(256, 6) void pbm_kernel(
    const float* __restrict__ lfeat,   // (16,1,16,H,W)
    const float* __restrict__ rfeat,
    const float* __restrict__ points,  // (1,N,2)
    const int* __restrict__ pW, const int* __restrict__ pH,
    float* __restrict__ out)           // (1,N,192,8)
{
    const int W = RFL_I(*pW), H = RFL_I(*pH);
    const int HW = W * H;
    const int n   = blockIdx.x;
    const int j   = blockIdx.y;        // same-n blocks: linear ids n+1024*j, 1024%8==0 -> same XCD
    const int tid = threadIdx.x;
    const int wv  = tid >> 6;
    const int l   = tid & 63;

    const float pxr = points[2 * n];
    const float pyr = points[2 * n + 1];
    const float pxf = floorf(pxr), pyf = floorf(pyr);
    const float fx  = RFL_F(pxr - pxf);
    const float fy  = RFL_F(pyr - pyf);
    const int   x0i = RFL_I((int)pxf);
    const int   y0i = RFL_I((int)pyf);

    __shared__ float sv[4][5][68];     // per-wave right strip (cols 0..67)
    __shared__ float sl[4][64];        // per-wave left 5x5 window (25 used)
    __shared__ float val4[48];

    const bool p0  = (wv == 3);
    const int  s_  = RFL_I(p0 ? 4 : 1);
    const int  lvl = RFL_I(p0 ? j + 8 : j);
    const int  off = RFL_I(p0 ? 49 : wv * 64 + 65);
    const int  DC  = RFL_I(p0 ? 48 : 64);

    // ---- strip column consts (col == lane): byte offsets + folded x-weights ----
    const int   cx   = x0i + s_ * (l - off);
    const int   cbo0 = min(max(cx, 0), W - 1) * 4;
    const int   cbo1 = min(max(cx + 1, 0), W - 1) * 4;
    const float ax0  = (((unsigned)cx       < (unsigned)W) ? 1.0f : 0.0f) * (1.0f - fx);
    const float ax1  = (((unsigned)(cx + 1) < (unsigned)W) ? 1.0f : 0.0f) * fx;

    // ---- wave-uniform row consts (SGPR): byte offsets + folded y-weights ----
    int ybo0[5], ybo1[5]; float by0[5], by1[5];
#pragma unroll
    for (int yy = 0; yy < 5; ++yy) {
        int yr = y0i + s_ * (yy - 2);
        ybo0[yy] = min(max(yr, 0), H - 1) * W * 4;
        ybo1[yy] = min(max(yr + 1, 0), H - 1) * W * 4;
        by0[yy]  = ((unsigned)yr       < (unsigned)H) ? (1.0f - fy) : 0.0f;
        by1[yy]  = ((unsigned)(yr + 1) < (unsigned)H) ? fy : 0.0f;
    }

    // ---- cleanup taps (pass-1 waves, lanes<20): col 64+(l&3), row l>>2 ----
    const int   dyc  = min(l >> 2, 4);
    const int   dcol = 64 + (l & 3);
    const int   dcx  = x0i + s_ * (dcol - off);
    const int   dbo0 = min(max(dcx, 0), W - 1) * 4;
    const int   dbo1 = min(max(dcx + 1, 0), W - 1) * 4;
    const float dax0 = (((unsigned)dcx       < (unsigned)W) ? 1.0f : 0.0f) * (1.0f - fx);
    const float dax1 = (((unsigned)(dcx + 1) < (unsigned)W) ? 1.0f : 0.0f) * fx;
    const int   dyr  = y0i + s_ * (dyc - 2);
    const int   dybo0 = min(max(dyr, 0), H - 1) * W * 4;
    const int   dybo1 = min(max(dyr + 1, 0), H - 1) * W * 4;
    const float dby0 = ((unsigned)dyr       < (unsigned)H) ? (1.0f - fy) : 0.0f;
    const float dby1 = ((unsigned)(dyr + 1) < (unsigned)H) ? fy : 0.0f;

    // ---- left window taps (lanes<25 meaningful, junk lanes harmless) ----
    const int   lyy = l / 5;
    const int   lxx = l - lyy * 5;
    const int   llx = x0i + s_ * (lxx - 2);
    const int   lly = y0i + s_ * (min(lyy, 4) - 2);
    const int   lbo0 = min(max(llx, 0), W - 1) * 4;
    const int   lbo1 = min(max(llx + 1, 0), W - 1) * 4;
    const float lax0 = (((unsigned)llx       < (unsigned)W) ? 1.0f : 0.0f) * (1.0f - fx);
    const float lax1 = (((unsigned)(llx + 1) < (unsigned)W) ? 1.0f : 0.0f) * fx;
    const int   lybo0 = min(max(lly, 0), H - 1) * W * 4;
    const int   lybo1 = min(max(lly + 1, 0), H - 1) * W * 4;
    const float lby0 = ((unsigned)lly       < (unsigned)H) ? (1.0f - fy) : 0.0f;
    const float lby1 = ((unsigned)(lly + 1) < (unsigned)H) ? fy : 0.0f;

    const char*  Rb  = (const char*)rfeat + (size_t)lvl * NCH * HW * 4;
    const char*  Lb  = (const char*)lfeat + (size_t)lvl * NCH * HW * 4;
    const size_t HW4 = (size_t)HW * 4;

    float acc = 0.0f;
#pragma unroll 1
    for (int c = 0; c < NCH; ++c) {
        const char* Rp = Rb + (size_t)c * HW4;
        const char* Lp = Lb + (size_t)c * HW4;

        // strip staging: unguarded (junk lanes write unread LDS slots)
#pragma unroll
        for (int yy = 0; yy < 5; ++yy) {
            float v00 = LOADF(Rp + ybo0[yy], cbo0);
            float v01 = LOADF(Rp + ybo0[yy], cbo1);
            float v10 = LOADF(Rp + ybo1[yy], cbo0);
            float v11 = LOADF(Rp + ybo1[yy], cbo1);
            float top = fmaf(ax0, v00, ax1 * v01);
            float bot = fmaf(ax0, v10, ax1 * v11);
            sv[wv][yy][l] = fmaf(by0[yy], top, by1[yy] * bot);
        }
        // cleanup cols 64..67 (must stay guarded: lanes>=20 would collide)
        if (!p0 && l < 20) {
            float v00 = LOADF(Rp + dybo0, dbo0);
            float v01 = LOADF(Rp + dybo0, dbo1);
            float v10 = LOADF(Rp + dybo1, dbo0);
            float v11 = LOADF(Rp + dybo1, dbo1);
            float top = fmaf(dax0, v00, dax1 * v01);
            float bot = fmaf(dax0, v10, dax1 * v11);
            sv[wv][dyc][dcol] = fmaf(dby0, top, dby1 * bot);
        }
        // left window: unguarded (lanes 25..63 write unread sl slots)
        {
            float v00 = LOADF(Lp + lybo0, lbo0);
            float v01 = LOADF(Lp + lybo0, lbo1);
            float v10 = LOADF(Lp + lybo1, lbo0);
            float v11 = LOADF(Lp + lybo1, lbo1);
            float top = fmaf(lax0, v00, lax1 * v01);
            float bot = fmaf(lax0, v10, lax1 * v11);
            sl[wv][l] = fmaf(lby0, top, lby1 * bot);
        }

        // taps (compiler inserts the lgkmcnt waits; DS pipe is in-order per wave)
        if (l < DC) {
            const float* slw = &sl[wv][0];
            float a0 = 0.f, a1 = 0.f;
#pragma unroll
            for (int yy = 0; yy < 5; ++yy) {
                const float* rp = &sv[wv][yy][DC - 1 - l];
                a0 += fabsf(slw[yy * 5 + 0] - rp[0]);
                a1 += fabsf(slw[yy * 5 + 1] - rp[1]);
                a0 += fabsf(slw[yy * 5 + 2] - rp[2]);
                a1 += fabsf(slw[yy * 5 + 3] - rp[3]);
                a0 += fabsf(slw[yy * 5 + 4] - rp[4]);
            }
            acc += a0 + a1;
        }
    }

    if (p0 && l < 48)
        val4[l] = 1.0f - expf(-acc * (1.0f / 400.0f));

    __syncthreads();                     // the ONLY block-wide barrier

    if (tid < MAXD) {                    // waves 0-2: d == tid
        float v1  = 1.0f - expf(-acc * (1.0f / 400.0f));
        float pos = (float)tid * (47.0f / 191.0f);
        float i0f = floorf(pos);
        int   i0  = (int)i0f;
        float w   = pos - i0f;
        int   i1  = min(i0 + 1, 47);
        float up  = val4[i0] + w * (val4[i1] - val4[i0]);
        out[((size_t)n * MAXD + tid) * 8 + j] = v1 + up;
    }
}

extern "C" void kernel_launch(void* const* d_in, const int* in_sizes, int n_in,
                              void* d_out, int out_size, void* d_ws, size_t ws_size,
                              hipStream_t stream) {
    const float* lf  = (const float*)d_in[0];
    const float* rf  = (const float*)d_in[1];
    const float* pts = (const float*)d_in[2];
    const int*   pW  = (const int*)d_in[3];
    const int*   pH  = (const int*)d_in[4];
    float* out = (float*)d_out;

    const int N = in_sizes[2] / 2;       // (B=1, N, 2)
    pbm_kernel<<<dim3(N, 8), 256, 0, stream>>>(lf, rf, pts, pW, pH, out);
}

// Round 7
// 252.121 us; speedup vs baseline: 130.9086x; 3.7767x over previous
//
#include <hip/hip_runtime.h>

#define MAXD 192
#define NCH  16

#define RFL_I(x) __builtin_amdgcn_readfirstlane(x)
#define RFL_F(x) __int_as_float(__builtin_amdgcn_readfirstlane(__float_as_int(x)))
#define RDL(v,k) __int_as_float(__builtin_amdgcn_readlane(__float_as_int(v), (k)))

__device__ __forceinline__ float samp(const float* __restrict__ p,
                                      int yb0, int yb1, float wy0, float wy1,
                                      int xb0, int xb1, float mxx0, float mxx1,
                                      float fx) {
    float v00 = p[yb0 + xb0] * mxx0, v01 = p[yb0 + xb1] * mxx1;
    float v10 = p[yb1 + xb0] * mxx0, v11 = p[yb1 + xb1] * mxx1;
    float top = v00 + fx * (v01 - v00);
    float bot = v10 + fx * (v11 - v10);
    return top * wy0 + bot * wy1;
}

// One block per (point n = blockIdx.x, level j = blockIdx.y).
// Waves 0-2: pass-1 (scale 1) disparity chunks [0,64),[64,128),[128,192).
// Wave 3:   pass-0 (scale 4, D=48), level j+8.
// Wave-private LDS strips; no inter-wave barrier except the val4 handoff.
// Left 5x5 window: computed per-lane, broadcast via v_readlane (no LDS).
// Bilinear frac weights / masks are block constants (coords = p + s*int).
// NOTE: do NOT pre-hoist per-lane constant arrays across the channel loop
// (R5/R6 scratch-spill failure); inline expressions + LICM only.
__global__ __launch_bounds__(256, 8) void pbm_kernel(
    const float* __restrict__ lfeat,   // (16,1,16,H,W)
    const float* __restrict__ rfeat,
    const float* __restrict__ points,  // (1,N,2)
    const int* __restrict__ pW, const int* __restrict__ pH,
    float* __restrict__ out)           // (1,N,192,8)
{
    const int W = RFL_I(*pW), H = RFL_I(*pH);
    const int HW = W * H;
    const int n   = blockIdx.x;
    const int j   = blockIdx.y;        // linear wg id = n + N*j; N%8==0 -> same-n same XCD
    const int tid = threadIdx.x;
    const int wv  = tid >> 6;
    const int l   = tid & 63;

    const float pxr = points[2 * n];
    const float pyr = points[2 * n + 1];
    const float pxf = floorf(pxr), pyf = floorf(pyr);
    const float fx  = RFL_F(pxr - pxf);
    const float fy  = RFL_F(pyr - pyf);
    const int   x0i = RFL_I((int)pxf);
    const int   y0i = RFL_I((int)pyf);

    __shared__ float sv[4][5][68];     // per-wave right strip
    __shared__ float val4[48];

    const bool p0  = (wv == 3);
    const int  s_  = RFL_I(p0 ? 4 : 1);
    const int  lvl = RFL_I(p0 ? j + 8 : j);
    const int  off = RFL_I(p0 ? 49 : wv * 64 + 65);
    const int  DC  = RFL_I(p0 ? 48 : 64);
    const int  stageN = RFL_I(p0 ? 52 : 64);

    // strip column constants (col == lane)
    const int   cx  = x0i + s_ * (l - off);
    const int   cb0 = min(max(cx, 0), W - 1);
    const int   cb1 = min(max(cx + 1, 0), W - 1);
    const float mx0 = ((unsigned)cx       < (unsigned)W) ? 1.0f : 0.0f;
    const float mx1 = ((unsigned)(cx + 1) < (unsigned)W) ? 1.0f : 0.0f;

    // cleanup taps (pass-1 waves): cols 64+(l&3), row l>>2, lanes<20
    const int   dyc  = min(l >> 2, 4);
    const int   dcol = 64 + (l & 3);
    const int   dcx  = x0i + s_ * (dcol - off);
    const int   db0  = min(max(dcx, 0), W - 1);
    const int   db1  = min(max(dcx + 1, 0), W - 1);
    const float dmx0 = ((unsigned)dcx       < (unsigned)W) ? 1.0f : 0.0f;
    const float dmx1 = ((unsigned)(dcx + 1) < (unsigned)W) ? 1.0f : 0.0f;
    const int   dyr  = y0i + s_ * (dyc - 2);
    const int   dyb0 = min(max(dyr, 0), H - 1) * W;
    const int   dyb1 = min(max(dyr + 1, 0), H - 1) * W;
    const float dwy0 = ((unsigned)dyr       < (unsigned)H) ? (1.0f - fy) : 0.0f;
    const float dwy1 = ((unsigned)(dyr + 1) < (unsigned)H) ? fy : 0.0f;

    // left window taps: lanes 0..24 meaningful
    const int   lq  = min(l, 24);
    const int   lyy = lq / 5;
    const int   lxx = lq - lyy * 5;
    const int   lx  = x0i + s_ * (lxx - 2);
    const int   ly  = y0i + s_ * (lyy - 2);
    const int   la0 = min(max(lx, 0), W - 1);
    const int   la1 = min(max(lx + 1, 0), W - 1);
    const float lmx0 = ((unsigned)lx       < (unsigned)W) ? 1.0f : 0.0f;
    const float lmx1 = ((unsigned)(lx + 1) < (unsigned)W) ? 1.0f : 0.0f;
    const int   lyb0 = min(max(ly, 0), H - 1) * W;
    const int   lyb1 = min(max(ly + 1, 0), H - 1) * W;
    const float lwy0 = ((unsigned)ly       < (unsigned)H) ? (1.0f - fy) : 0.0f;
    const float lwy1 = ((unsigned)(ly + 1) < (unsigned)H) ? fy : 0.0f;

    const float* Rb = rfeat + (size_t)(lvl * NCH) * HW;
    const float* Lb = lfeat + (size_t)(lvl * NCH) * HW;

    float acc = 0.0f;
#pragma unroll 1
    for (int c = 0; c < NCH; ++c) {
        const float* Rp = Rb + (size_t)c * HW;
        const float* Lp = Lb + (size_t)c * HW;

        if (l < stageN) {
#pragma unroll 1
            for (int yy = 0; yy < 5; ++yy) {
                int   yr  = y0i + s_ * (yy - 2);          // uniform -> SALU
                int   yb0 = min(max(yr, 0), H - 1) * W;
                int   yb1 = min(max(yr + 1, 0), H - 1) * W;
                float wy0 = ((unsigned)yr       < (unsigned)H) ? (1.0f - fy) : 0.0f;
                float wy1 = ((unsigned)(yr + 1) < (unsigned)H) ? fy : 0.0f;
                sv[wv][yy][l] = samp(Rp, yb0, yb1, wy0, wy1, cb0, cb1, mx0, mx1, fx);
            }
        }
        if (!p0 && l < 20)
            sv[wv][dyc][dcol] = samp(Rp, dyb0, dyb1, dwy0, dwy1, db0, db1, dmx0, dmx1, fx);

        // left window value for this lane's (lyy,lxx); broadcast below
        float lval = samp(Lp, lyb0, lyb1, lwy0, lwy1, la0, la1, lmx0, lmx1, fx);

        // broadcast left window into wave-uniform scalars (no LDS, no array)
        float sk00 = RDL(lval, 0),  sk01 = RDL(lval, 1),  sk02 = RDL(lval, 2);
        float sk03 = RDL(lval, 3),  sk04 = RDL(lval, 4);
        float sk05 = RDL(lval, 5),  sk06 = RDL(lval, 6),  sk07 = RDL(lval, 7);
        float sk08 = RDL(lval, 8),  sk09 = RDL(lval, 9);
        float sk10 = RDL(lval, 10), sk11 = RDL(lval, 11), sk12 = RDL(lval, 12);
        float sk13 = RDL(lval, 13), sk14 = RDL(lval, 14);
        float sk15 = RDL(lval, 15), sk16 = RDL(lval, 16), sk17 = RDL(lval, 17);
        float sk18 = RDL(lval, 18), sk19 = RDL(lval, 19);
        float sk20 = RDL(lval, 20), sk21 = RDL(lval, 21), sk22 = RDL(lval, 22);
        float sk23 = RDL(lval, 23), sk24 = RDL(lval, 24);

        if (l < DC) {
            float a0 = 0.f, a1 = 0.f;
            {
                const float* rp = &sv[wv][0][DC - 1 - l];
                a0 += fabsf(sk00 - rp[0]); a1 += fabsf(sk01 - rp[1]);
                a0 += fabsf(sk02 - rp[2]); a1 += fabsf(sk03 - rp[3]);
                a0 += fabsf(sk04 - rp[4]);
            }
            {
                const float* rp = &sv[wv][1][DC - 1 - l];
                a0 += fabsf(sk05 - rp[0]); a1 += fabsf(sk06 - rp[1]);
                a0 += fabsf(sk07 - rp[2]); a1 += fabsf(sk08 - rp[3]);
                a0 += fabsf(sk09 - rp[4]);
            }
            {
                const float* rp = &sv[wv][2][DC - 1 - l];
                a0 += fabsf(sk10 - rp[0]); a1 += fabsf(sk11 - rp[1]);
                a0 += fabsf(sk12 - rp[2]); a1 += fabsf(sk13 - rp[3]);
                a0 += fabsf(sk14 - rp[4]);
            }
            {
                const float* rp = &sv[wv][3][DC - 1 - l];
                a0 += fabsf(sk15 - rp[0]); a1 += fabsf(sk16 - rp[1]);
                a0 += fabsf(sk17 - rp[2]); a1 += fabsf(sk18 - rp[3]);
                a0 += fabsf(sk19 - rp[4]);
            }
            {
                const float* rp = &sv[wv][4][DC - 1 - l];
                a0 += fabsf(sk20 - rp[0]); a1 += fabsf(sk21 - rp[1]);
                a0 += fabsf(sk22 - rp[2]); a1 += fabsf(sk23 - rp[3]);
                a0 += fabsf(sk24 - rp[4]);
            }
            acc += a0 + a1;
        }
    }

    if (p0 && l < 48)
        val4[l] = 1.0f - expf(-acc * (1.0f / 400.0f));

    __syncthreads();                     // the ONLY block-wide barrier

    if (tid < MAXD) {                    // waves 0-2: d == tid
        float v1  = 1.0f - expf(-acc * (1.0f / 400.0f));
        float pos = (float)tid * (47.0f / 191.0f);
        float i0f = floorf(pos);
        int   i0  = (int)i0f;
        float w   = pos - i0f;
        int   i1  = min(i0 + 1, 47);
        float up  = val4[i0] + w * (val4[i1] - val4[i0]);
        out[((size_t)n * MAXD + tid) * 8 + j] = v1 + up;
    }
}

extern "C" void kernel_launch(void* const* d_in, const int* in_sizes, int n_in,
                              void* d_out, int out_size, void* d_ws, size_t ws_size,
                              hipStream_t stream) {
    const float* lf  = (const float*)d_in[0];
    const float* rf  = (const float*)d_in[1];
    const float* pts = (const float*)d_in[2];
    const int*   pW  = (const int*)d_in[3];
    const int*   pH  = (const int*)d_in[4];
    float* out = (float*)d_out;

    const int N = in_sizes[2] / 2;       // (B=1, N, 2)
    pbm_kernel<<<dim3(N, 8), 256, 0, stream>>>(lf, rf, pts, pW, pH, out);
}